// Round 2
// baseline (3846.434 us; speedup 1.0000x reference)
//
#include <hip/hip_runtime.h>
#include <math.h>

#define T 32000
#define B 8
#define RES 32
#define SKIPC 32
#define NDIL 10
#define NLAYERS 20

// ---------------- fast transcendentals (v_exp_f32 / v_rcp_f32) ----------------
__device__ __forceinline__ float fast_rcp(float x) { return __builtin_amdgcn_rcpf(x); }
__device__ __forceinline__ float fast_exp2(float x) { return __builtin_amdgcn_exp2f(x); }
// sigmoid(x) = 1/(1+exp(-x)) = rcp(1 + exp2(-x*log2e))
__device__ __forceinline__ float fast_sigmoid(float x) {
    return fast_rcp(1.f + fast_exp2(-1.4426950408889634f * x));
}
// tanh(x) = 1 - 2/(1+exp(2x)) = 1 - 2*rcp(1 + exp2(x*2*log2e))
__device__ __forceinline__ float fast_tanh(float x) {
    return 1.f - 2.f * fast_rcp(1.f + fast_exp2(2.8853900817779268f * x));
}

// ---------------- weight transpose ----------------
// res_w1: [10][64][32][3]  -> w1t: [10][32][3][64]   (contig in o for s_load)
// res_w2: [10][64][32](x1) -> w2t: [10][32][64]
__global__ void transpose_weights(const float* __restrict__ w1,
                                  const float* __restrict__ w2,
                                  float* __restrict__ w1t,
                                  float* __restrict__ w2t) {
    int idx = blockIdx.x * blockDim.x + threadIdx.x;
    if (idx < NDIL * 64 * 32 * 3) {
        int i = idx;
        int k = i % 3; i /= 3;
        int c = i % 32; i /= 32;
        int o = i % 64; i /= 64;
        int l = i;
        w1t[(((l * 32 + c) * 3 + k) * 64) + o] = w1[idx];
    }
    if (idx < NDIL * 64 * 32) {
        int i = idx;
        int c = i % 32; i /= 32;
        int o = i % 64; i /= 64;
        int l = i;
        w2t[(l * 32 + c) * 64 + o] = w2[idx];
    }
}

// ---------------- conv1: [B,1,T] -> [B,32,T], k=3 causal ----------------
__global__ void conv1_kernel(const float* __restrict__ x,
                             const float* __restrict__ w,   // [32][1][3]
                             float* __restrict__ h) {
    int t = blockIdx.x * blockDim.x + threadIdx.x;
    int b = blockIdx.y;
    if (t >= T) return;
    const float* xb = x + (size_t)b * T;
    float x2 = xb[t];
    float x1 = (t >= 1) ? xb[t - 1] : 0.f;
    float x0 = (t >= 2) ? xb[t - 2] : 0.f;
#pragma unroll
    for (int o = 0; o < RES; o++) {
        float v = w[o * 3 + 0] * x0 + w[o * 3 + 1] * x1 + w[o * 3 + 2] * x2;
        h[((size_t)(b * RES + o)) * T + t] = v;
    }
}

// ---------------- residual layer ----------------
// y = dilated_conv(h_in, w1) [64ch]; g = tanh(y[:32])*sigmoid(y[32:]);
// z = w2 @ g [64ch]; h_out = h_in + z[:32]; skip (+)= z[32:]
template <bool FIRST>
__global__ __launch_bounds__(256, 4) void res_layer(
        const float* __restrict__ h_in, float* __restrict__ h_out,
        float* __restrict__ skip,
        const float* __restrict__ w1t,   // [32][3][64] this layer
        const float* __restrict__ w2t,   // [32][64] this layer
        int d) {
    int t = blockIdx.x * blockDim.x + threadIdx.x;
    int b = blockIdx.y;

    float acc[64];
#pragma unroll
    for (int o = 0; o < 64; o++) acc[o] = 0.f;
    float res[RES];   // h_in at (c, t) saved for residual add

    const float* hb = h_in + (size_t)b * RES * T;
    const bool interior = (blockIdx.x * blockDim.x) >= 2 * d;

    if (interior) {
        // no bounds checks needed: t >= 2d for every thread in this block
#pragma unroll 4
        for (int c = 0; c < RES; c++) {
            const float* hc = hb + (size_t)c * T;
            float x2 = hc[t];
            float x1 = hc[t - d];
            float x0 = hc[t - 2 * d];
            res[c] = x2;
            const float* wc = w1t + c * 3 * 64;
#pragma unroll
            for (int o = 0; o < 64; o++) {
                acc[o] += wc[o] * x0 + wc[64 + o] * x1 + wc[128 + o] * x2;
            }
        }
    } else {
#pragma unroll 4
        for (int c = 0; c < RES; c++) {
            const float* hc = hb + (size_t)c * T;
            float x2 = hc[t];
            float x1 = (t >= d) ? hc[t - d] : 0.f;
            float x0 = (t >= 2 * d) ? hc[t - 2 * d] : 0.f;
            res[c] = x2;
            const float* wc = w1t + c * 3 * 64;
#pragma unroll
            for (int o = 0; o < 64; o++) {
                acc[o] += wc[o] * x0 + wc[64 + o] * x1 + wc[128 + o] * x2;
            }
        }
    }

    // prefetch skip (latency hides under gate + 1x1 below)
    float skv[SKIPC];
    if (!FIRST) {
#pragma unroll
        for (int o = 0; o < SKIPC; o++) {
            skv[o] = skip[((size_t)(b * SKIPC + o)) * T + t];
        }
    }

    float g[RES];
#pragma unroll
    for (int o = 0; o < RES; o++) {
        g[o] = fast_tanh(acc[o]) * fast_sigmoid(acc[o + RES]);
    }

    float z[64];
#pragma unroll
    for (int o = 0; o < 64; o++) z[o] = 0.f;
#pragma unroll 4
    for (int c = 0; c < RES; c++) {
        float gc = g[c];
        const float* wc = w2t + c * 64;
#pragma unroll
        for (int o = 0; o < 64; o++) z[o] += wc[o] * gc;
    }

#pragma unroll
    for (int o = 0; o < RES; o++) {
        size_t off = ((size_t)(b * RES + o)) * T + t;
        h_out[off] = res[o] + z[o];
    }
#pragma unroll
    for (int o = 0; o < SKIPC; o++) {
        size_t off = ((size_t)(b * SKIPC + o)) * T + t;
        if (FIRST) skip[off] = z[32 + o];
        else       skip[off] = skv[o] + z[32 + o];
    }
}

// ---------------- post2: tanh(skip) -> conv 32->16 k3 -> tanh ----------------
__global__ void post2_kernel(const float* __restrict__ skip,
                             const float* __restrict__ w,    // [16][32][3]
                             float* __restrict__ out16) {
    int t = blockIdx.x * blockDim.x + threadIdx.x;
    int b = blockIdx.y;
    float acc[16];
#pragma unroll
    for (int o = 0; o < 16; o++) acc[o] = 0.f;
#pragma unroll 4
    for (int c = 0; c < 32; c++) {
        const float* sc = skip + ((size_t)(b * 32 + c)) * T;
        float v2 = fast_tanh(sc[t]);
        float v1 = (t >= 1) ? fast_tanh(sc[t - 1]) : 0.f;
        float v0 = (t >= 2) ? fast_tanh(sc[t - 2]) : 0.f;
#pragma unroll
        for (int o = 0; o < 16; o++) {
            const float* wo = w + (o * 32 + c) * 3;
            acc[o] += wo[0] * v0 + wo[1] * v1 + wo[2] * v2;
        }
    }
#pragma unroll
    for (int o = 0; o < 16; o++)
        out16[((size_t)(b * 16 + o)) * T + t] = fast_tanh(acc[o]);
}

// ---------------- post3: conv 16->8 k3 -> tanh ----------------
__global__ void post3_kernel(const float* __restrict__ in16,
                             const float* __restrict__ w,    // [8][16][3]
                             float* __restrict__ out8) {
    int t = blockIdx.x * blockDim.x + threadIdx.x;
    int b = blockIdx.y;
    float acc[8];
#pragma unroll
    for (int o = 0; o < 8; o++) acc[o] = 0.f;
#pragma unroll
    for (int c = 0; c < 16; c++) {
        const float* sc = in16 + ((size_t)(b * 16 + c)) * T;
        float v2 = sc[t];
        float v1 = (t >= 1) ? sc[t - 1] : 0.f;
        float v0 = (t >= 2) ? sc[t - 2] : 0.f;
#pragma unroll
        for (int o = 0; o < 8; o++) {
            const float* wo = w + (o * 16 + c) * 3;
            acc[o] += wo[0] * v0 + wo[1] * v1 + wo[2] * v2;
        }
    }
#pragma unroll
    for (int o = 0; o < 8; o++)
        out8[((size_t)(b * 8 + o)) * T + t] = fast_tanh(acc[o]);
}

// ---------------- post4: conv 8->1 k3 -> tanh ----------------
__global__ void post4_kernel(const float* __restrict__ in8,
                             const float* __restrict__ w,    // [1][8][3]
                             float* __restrict__ out1) {
    int t = blockIdx.x * blockDim.x + threadIdx.x;
    int b = blockIdx.y;
    float acc = 0.f;
#pragma unroll
    for (int c = 0; c < 8; c++) {
        const float* sc = in8 + ((size_t)(b * 8 + c)) * T;
        float v2 = sc[t];
        float v1 = (t >= 1) ? sc[t - 1] : 0.f;
        float v0 = (t >= 2) ? sc[t - 2] : 0.f;
        const float* wo = w + c * 3;
        acc += wo[0] * v0 + wo[1] * v1 + wo[2] * v2;
    }
    out1[(size_t)b * T + t] = fast_tanh(acc);
}

// ---------------- vnn head: lin(k=16) + quadratic Volterra ----------------
__global__ void vnn_kernel(const float* __restrict__ in1,   // [B][T]
                           const float* __restrict__ w1,    // [1][1][16]
                           const float* __restrict__ w2,    // [6][1][16]
                           float* __restrict__ out) {       // [B][T]
    int t = blockIdx.x * blockDim.x + threadIdx.x;
    int b = blockIdx.y;
    const float* xb = in1 + (size_t)b * T;
    float tap[16];
#pragma unroll
    for (int k = 0; k < 16; k++) {
        int ti = t - 15 + k;
        tap[k] = (ti >= 0) ? xb[ti] : 0.f;
    }
    float lin = 0.f;
#pragma unroll
    for (int k = 0; k < 16; k++) lin += w1[k] * tap[k];
    float s[6];
#pragma unroll
    for (int q = 0; q < 6; q++) {
        float a = 0.f;
#pragma unroll
        for (int k = 0; k < 16; k++) a += w2[q * 16 + k] * tap[k];
        s[q] = a;
    }
    float quad = s[0] * s[3] + s[1] * s[4] + s[2] * s[5];
    out[(size_t)b * T + t] = lin + quad;
}

extern "C" void kernel_launch(void* const* d_in, const int* in_sizes, int n_in,
                              void* d_out, int out_size, void* d_ws, size_t ws_size,
                              hipStream_t stream) {
    const float* x       = (const float*)d_in[0];
    const float* conv1_w = (const float*)d_in[1];
    const float* res_w1  = (const float*)d_in[2];
    const float* res_w2  = (const float*)d_in[3];
    const float* post2_w = (const float*)d_in[4];
    const float* post3_w = (const float*)d_in[5];
    const float* post4_w = (const float*)d_in[6];
    const float* vnn1_w  = (const float*)d_in[7];
    const float* vnn2_w  = (const float*)d_in[8];
    float* out = (float*)d_out;

    // workspace layout (bytes)
    char* ws = (char*)d_ws;
    const size_t SZ_H    = (size_t)B * RES * T * 4;     // 32.768 MB
    const size_t SZ_O16  = (size_t)B * 16 * T * 4;
    const size_t SZ_O8   = (size_t)B * 8 * T * 4;
    const size_t SZ_O1   = (size_t)B * 1 * T * 4;
    float* hA    = (float*)(ws);
    float* hB    = (float*)(ws + SZ_H);
    float* skip  = (float*)(ws + 2 * SZ_H);
    float* out16 = (float*)(ws + 3 * SZ_H);
    float* out8  = (float*)(ws + 3 * SZ_H + SZ_O16);
    float* out1  = (float*)(ws + 3 * SZ_H + SZ_O16 + SZ_O8);
    float* w1t   = (float*)(ws + 3 * SZ_H + SZ_O16 + SZ_O8 + SZ_O1);
    float* w2t   = (float*)(ws + 3 * SZ_H + SZ_O16 + SZ_O8 + SZ_O1
                               + (size_t)NDIL * 32 * 3 * 64 * 4);

    dim3 blk(256);
    dim3 grd(T / 256, B);   // T = 32000 = 125 * 256

    transpose_weights<<<dim3((NDIL * 64 * 32 * 3 + 255) / 256), blk, 0, stream>>>(
        res_w1, res_w2, w1t, w2t);

    conv1_kernel<<<grd, blk, 0, stream>>>(x, conv1_w, hA);

    const float* cur = hA;
    float* nxt = hB;
    for (int l = 0; l < NLAYERS; l++) {
        int i = l % NDIL;
        int d = 1 << i;
        const float* w1l = w1t + (size_t)i * 32 * 3 * 64;
        const float* w2l = w2t + (size_t)i * 32 * 64;
        if (l == 0)
            res_layer<true><<<grd, blk, 0, stream>>>(cur, nxt, skip, w1l, w2l, d);
        else
            res_layer<false><<<grd, blk, 0, stream>>>(cur, nxt, skip, w1l, w2l, d);
        const float* tmp = nxt;
        nxt = (float*)cur;
        cur = tmp;
    }

    post2_kernel<<<grd, blk, 0, stream>>>(skip, post2_w, out16);
    post3_kernel<<<grd, blk, 0, stream>>>(out16, post3_w, out8);
    post4_kernel<<<grd, blk, 0, stream>>>(out8, post4_w, out1);
    vnn_kernel<<<grd, blk, 0, stream>>>(out1, vnn1_w, vnn2_w, out);
}

// Round 3
// 2389.137 us; speedup vs baseline: 1.6100x; 1.6100x over previous
//
#include <hip/hip_runtime.h>
#include <math.h>

#define T 32000
#define B 8
#define RES 32
#define SKIPC 32
#define NDIL 10
#define NLAYERS 20

// ---------------- fast transcendentals (v_exp_f32 / v_rcp_f32) ----------------
__device__ __forceinline__ float fast_rcp(float x) { return __builtin_amdgcn_rcpf(x); }
__device__ __forceinline__ float fast_exp2(float x) { return __builtin_amdgcn_exp2f(x); }
// sigmoid(x) = 1/(1+exp(-x)) = rcp(1 + exp2(-x*log2e))
__device__ __forceinline__ float fast_sigmoid(float x) {
    return fast_rcp(1.f + fast_exp2(-1.4426950408889634f * x));
}
// tanh(x) = 1 - 2/(1+exp(2x)) = 1 - 2*rcp(1 + exp2(x*2*log2e))
__device__ __forceinline__ float fast_tanh(float x) {
    return 1.f - 2.f * fast_rcp(1.f + fast_exp2(2.8853900817779268f * x));
}

// ---------------- weight transpose ----------------
// res_w1: [10][64][32][3]  -> w1t: [10][32][3][64]   (contig in o for s_load)
// res_w2: [10][64][32](x1) -> w2t: [10][32][64]
__global__ void transpose_weights(const float* __restrict__ w1,
                                  const float* __restrict__ w2,
                                  float* __restrict__ w1t,
                                  float* __restrict__ w2t) {
    int idx = blockIdx.x * blockDim.x + threadIdx.x;
    if (idx < NDIL * 64 * 32 * 3) {
        int i = idx;
        int k = i % 3; i /= 3;
        int c = i % 32; i /= 32;
        int o = i % 64; i /= 64;
        int l = i;
        w1t[(((l * 32 + c) * 3 + k) * 64) + o] = w1[idx];
    }
    if (idx < NDIL * 64 * 32) {
        int i = idx;
        int c = i % 32; i /= 32;
        int o = i % 64; i /= 64;
        int l = i;
        w2t[(l * 32 + c) * 64 + o] = w2[idx];
    }
}

// ---------------- conv1: [B,1,T] -> [B,32,T], k=3 causal ----------------
__global__ void conv1_kernel(const float* __restrict__ x,
                             const float* __restrict__ w,   // [32][1][3]
                             float* __restrict__ h) {
    int t = blockIdx.x * blockDim.x + threadIdx.x;
    int b = blockIdx.y;
    if (t >= T) return;
    const float* xb = x + (size_t)b * T;
    float x2 = xb[t];
    float x1 = (t >= 1) ? xb[t - 1] : 0.f;
    float x0 = (t >= 2) ? xb[t - 2] : 0.f;
#pragma unroll
    for (int o = 0; o < RES; o++) {
        float v = w[o * 3 + 0] * x0 + w[o * 3 + 1] * x1 + w[o * 3 + 2] * x2;
        h[((size_t)(b * RES + o)) * T + t] = v;
    }
}

// ---------------- residual layer ----------------
// y = dilated_conv(h_in, w1) [64ch]; g = tanh(y[:32])*sigmoid(y[32:]);
// z = w2 @ g [64ch]; h_out = h_in + z[:32]; skip (+)= z[32:]
// Register discipline (R2 post-mortem): keep live set small. No res[] save,
// no skip prefetch, no c-loop unroll — R2's combo spilled (WRITE_SIZE 64->313MB).
template <bool FIRST>
__global__ __launch_bounds__(256) void res_layer(
        const float* __restrict__ h_in, float* __restrict__ h_out,
        float* __restrict__ skip,
        const float* __restrict__ w1t,   // [32][3][64] this layer
        const float* __restrict__ w2t,   // [32][64] this layer
        int d) {
    int t = blockIdx.x * blockDim.x + threadIdx.x;
    int b = blockIdx.y;

    float acc[64];
#pragma unroll
    for (int o = 0; o < 64; o++) acc[o] = 0.f;

    const float* hb = h_in + (size_t)b * RES * T;
    const bool interior = (blockIdx.x * blockDim.x) >= 2 * d;  // block-uniform

    if (interior) {
        for (int c = 0; c < RES; c++) {
            const float* hc = hb + (size_t)c * T;
            float x2 = hc[t];
            float x1 = hc[t - d];
            float x0 = hc[t - 2 * d];
            const float* wc = w1t + c * 3 * 64;
#pragma unroll
            for (int o = 0; o < 64; o++) {
                acc[o] += wc[o] * x0 + wc[64 + o] * x1 + wc[128 + o] * x2;
            }
        }
    } else {
        for (int c = 0; c < RES; c++) {
            const float* hc = hb + (size_t)c * T;
            float x2 = hc[t];
            float x1 = (t >= d) ? hc[t - d] : 0.f;
            float x0 = (t >= 2 * d) ? hc[t - 2 * d] : 0.f;
            const float* wc = w1t + c * 3 * 64;
#pragma unroll
            for (int o = 0; o < 64; o++) {
                acc[o] += wc[o] * x0 + wc[64 + o] * x1 + wc[128 + o] * x2;
            }
        }
    }

    float g[RES];
#pragma unroll
    for (int o = 0; o < RES; o++) {
        g[o] = fast_tanh(acc[o]) * fast_sigmoid(acc[o + RES]);
    }

    float z[64];
#pragma unroll
    for (int o = 0; o < 64; o++) z[o] = 0.f;
    for (int c = 0; c < RES; c++) {
        float gc = g[c];
        const float* wc = w2t + c * 64;
#pragma unroll
        for (int o = 0; o < 64; o++) z[o] += wc[o] * gc;
    }

#pragma unroll
    for (int o = 0; o < RES; o++) {
        size_t off = ((size_t)(b * RES + o)) * T + t;
        h_out[off] = h_in[off] + z[o];   // h_in reload: L1-hot from conv loop
    }
#pragma unroll
    for (int o = 0; o < SKIPC; o++) {
        size_t off = ((size_t)(b * SKIPC + o)) * T + t;
        if (FIRST) skip[off] = z[32 + o];
        else       skip[off] = skip[off] + z[32 + o];
    }
}

// ---------------- post2: tanh(skip) -> conv 32->16 k3 -> tanh ----------------
__global__ void post2_kernel(const float* __restrict__ skip,
                             const float* __restrict__ w,    // [16][32][3]
                             float* __restrict__ out16) {
    int t = blockIdx.x * blockDim.x + threadIdx.x;
    int b = blockIdx.y;
    float acc[16];
#pragma unroll
    for (int o = 0; o < 16; o++) acc[o] = 0.f;
    for (int c = 0; c < 32; c++) {
        const float* sc = skip + ((size_t)(b * 32 + c)) * T;
        float v2 = fast_tanh(sc[t]);
        float v1 = (t >= 1) ? fast_tanh(sc[t - 1]) : 0.f;
        float v0 = (t >= 2) ? fast_tanh(sc[t - 2]) : 0.f;
#pragma unroll
        for (int o = 0; o < 16; o++) {
            const float* wo = w + (o * 32 + c) * 3;
            acc[o] += wo[0] * v0 + wo[1] * v1 + wo[2] * v2;
        }
    }
#pragma unroll
    for (int o = 0; o < 16; o++)
        out16[((size_t)(b * 16 + o)) * T + t] = fast_tanh(acc[o]);
}

// ---------------- post3: conv 16->8 k3 -> tanh ----------------
__global__ void post3_kernel(const float* __restrict__ in16,
                             const float* __restrict__ w,    // [8][16][3]
                             float* __restrict__ out8) {
    int t = blockIdx.x * blockDim.x + threadIdx.x;
    int b = blockIdx.y;
    float acc[8];
#pragma unroll
    for (int o = 0; o < 8; o++) acc[o] = 0.f;
    for (int c = 0; c < 16; c++) {
        const float* sc = in16 + ((size_t)(b * 16 + c)) * T;
        float v2 = sc[t];
        float v1 = (t >= 1) ? sc[t - 1] : 0.f;
        float v0 = (t >= 2) ? sc[t - 2] : 0.f;
#pragma unroll
        for (int o = 0; o < 8; o++) {
            const float* wo = w + (o * 16 + c) * 3;
            acc[o] += wo[0] * v0 + wo[1] * v1 + wo[2] * v2;
        }
    }
#pragma unroll
    for (int o = 0; o < 8; o++)
        out8[((size_t)(b * 8 + o)) * T + t] = fast_tanh(acc[o]);
}

// ---------------- post4: conv 8->1 k3 -> tanh ----------------
__global__ void post4_kernel(const float* __restrict__ in8,
                             const float* __restrict__ w,    // [1][8][3]
                             float* __restrict__ out1) {
    int t = blockIdx.x * blockDim.x + threadIdx.x;
    int b = blockIdx.y;
    float acc = 0.f;
#pragma unroll
    for (int c = 0; c < 8; c++) {
        const float* sc = in8 + ((size_t)(b * 8 + c)) * T;
        float v2 = sc[t];
        float v1 = (t >= 1) ? sc[t - 1] : 0.f;
        float v0 = (t >= 2) ? sc[t - 2] : 0.f;
        const float* wo = w + c * 3;
        acc += wo[0] * v0 + wo[1] * v1 + wo[2] * v2;
    }
    out1[(size_t)b * T + t] = fast_tanh(acc);
}

// ---------------- vnn head: lin(k=16) + quadratic Volterra ----------------
__global__ void vnn_kernel(const float* __restrict__ in1,   // [B][T]
                           const float* __restrict__ w1,    // [1][1][16]
                           const float* __restrict__ w2,    // [6][1][16]
                           float* __restrict__ out) {       // [B][T]
    int t = blockIdx.x * blockDim.x + threadIdx.x;
    int b = blockIdx.y;
    const float* xb = in1 + (size_t)b * T;
    float tap[16];
#pragma unroll
    for (int k = 0; k < 16; k++) {
        int ti = t - 15 + k;
        tap[k] = (ti >= 0) ? xb[ti] : 0.f;
    }
    float lin = 0.f;
#pragma unroll
    for (int k = 0; k < 16; k++) lin += w1[k] * tap[k];
    float s[6];
#pragma unroll
    for (int q = 0; q < 6; q++) {
        float a = 0.f;
#pragma unroll
        for (int k = 0; k < 16; k++) a += w2[q * 16 + k] * tap[k];
        s[q] = a;
    }
    float quad = s[0] * s[3] + s[1] * s[4] + s[2] * s[5];
    out[(size_t)b * T + t] = lin + quad;
}

extern "C" void kernel_launch(void* const* d_in, const int* in_sizes, int n_in,
                              void* d_out, int out_size, void* d_ws, size_t ws_size,
                              hipStream_t stream) {
    const float* x       = (const float*)d_in[0];
    const float* conv1_w = (const float*)d_in[1];
    const float* res_w1  = (const float*)d_in[2];
    const float* res_w2  = (const float*)d_in[3];
    const float* post2_w = (const float*)d_in[4];
    const float* post3_w = (const float*)d_in[5];
    const float* post4_w = (const float*)d_in[6];
    const float* vnn1_w  = (const float*)d_in[7];
    const float* vnn2_w  = (const float*)d_in[8];
    float* out = (float*)d_out;

    // workspace layout (bytes)
    char* ws = (char*)d_ws;
    const size_t SZ_H    = (size_t)B * RES * T * 4;     // 32.768 MB
    const size_t SZ_O16  = (size_t)B * 16 * T * 4;
    const size_t SZ_O8   = (size_t)B * 8 * T * 4;
    const size_t SZ_O1   = (size_t)B * 1 * T * 4;
    float* hA    = (float*)(ws);
    float* hB    = (float*)(ws + SZ_H);
    float* skip  = (float*)(ws + 2 * SZ_H);
    float* out16 = (float*)(ws + 3 * SZ_H);
    float* out8  = (float*)(ws + 3 * SZ_H + SZ_O16);
    float* out1  = (float*)(ws + 3 * SZ_H + SZ_O16 + SZ_O8);
    float* w1t   = (float*)(ws + 3 * SZ_H + SZ_O16 + SZ_O8 + SZ_O1);
    float* w2t   = (float*)(ws + 3 * SZ_H + SZ_O16 + SZ_O8 + SZ_O1
                               + (size_t)NDIL * 32 * 3 * 64 * 4);

    dim3 blk(256);
    dim3 grd(T / 256, B);   // T = 32000 = 125 * 256

    transpose_weights<<<dim3((NDIL * 64 * 32 * 3 + 255) / 256), blk, 0, stream>>>(
        res_w1, res_w2, w1t, w2t);

    conv1_kernel<<<grd, blk, 0, stream>>>(x, conv1_w, hA);

    const float* cur = hA;
    float* nxt = hB;
    for (int l = 0; l < NLAYERS; l++) {
        int i = l % NDIL;
        int d = 1 << i;
        const float* w1l = w1t + (size_t)i * 32 * 3 * 64;
        const float* w2l = w2t + (size_t)i * 32 * 64;
        if (l == 0)
            res_layer<true><<<grd, blk, 0, stream>>>(cur, nxt, skip, w1l, w2l, d);
        else
            res_layer<false><<<grd, blk, 0, stream>>>(cur, nxt, skip, w1l, w2l, d);
        const float* tmp = nxt;
        nxt = (float*)cur;
        cur = tmp;
    }

    post2_kernel<<<grd, blk, 0, stream>>>(skip, post2_w, out16);
    post3_kernel<<<grd, blk, 0, stream>>>(out16, post3_w, out8);
    post4_kernel<<<grd, blk, 0, stream>>>(out8, post4_w, out1);
    vnn_kernel<<<grd, blk, 0, stream>>>(out1, vnn1_w, vnn2_w, out);
}

// Round 4
// 1512.552 us; speedup vs baseline: 2.5430x; 1.5795x over previous
//
#include <hip/hip_runtime.h>
#include <math.h>

#define T 32000
#define B 8
#define RES 32
#define SKIPC 32
#define NDIL 10
#define NLAYERS 20

// ---------------- fast transcendentals (v_exp_f32 / v_rcp_f32) ----------------
__device__ __forceinline__ float fast_rcp(float x) { return __builtin_amdgcn_rcpf(x); }
__device__ __forceinline__ float fast_exp2(float x) { return __builtin_amdgcn_exp2f(x); }
__device__ __forceinline__ float fast_sigmoid(float x) {
    return fast_rcp(1.f + fast_exp2(-1.4426950408889634f * x));
}
__device__ __forceinline__ float fast_tanh(float x) {
    return 1.f - 2.f * fast_rcp(1.f + fast_exp2(2.8853900817779268f * x));
}

// ---------------- weight repack for half-split res_layer ----------------
// res_w1: [10][64][32][3] -> w1p: [10][2][32][3][2][16]
//   (l, o, c, k) -> (l, h=(o%32)/16, c, k, p=o/32, j=o%16)
// res_w2: [10][64][32]    -> w2p: [10][2][32][2][16]
__global__ void repack_weights(const float* __restrict__ w1,
                               const float* __restrict__ w2,
                               float* __restrict__ w1p,
                               float* __restrict__ w2p) {
    int idx = blockIdx.x * blockDim.x + threadIdx.x;
    if (idx < NDIL * 64 * 32 * 3) {
        int i = idx;
        int k = i % 3; i /= 3;
        int c = i % 32; i /= 32;
        int o = i % 64; i /= 64;
        int l = i;
        int p = o / 32, rem = o % 32, h = rem / 16, j = rem % 16;
        w1p[(((((l * 2 + h) * 32 + c) * 3 + k) * 2 + p) * 16) + j] = w1[idx];
    }
    if (idx < NDIL * 64 * 32) {
        int i = idx;
        int c = i % 32; i /= 32;
        int o = i % 64; i /= 64;
        int l = i;
        int p = o / 32, rem = o % 32, h = rem / 16, j = rem % 16;
        w2p[((((l * 2 + h) * 32 + c) * 2 + p) * 16) + j] = w2[idx];
    }
}

// ---------------- conv1: [B,1,T] -> [B,32,T], k=3 causal ----------------
__global__ void conv1_kernel(const float* __restrict__ x,
                             const float* __restrict__ w,   // [32][1][3]
                             float* __restrict__ h) {
    int t = blockIdx.x * blockDim.x + threadIdx.x;
    int b = blockIdx.y;
    if (t >= T) return;
    const float* xb = x + (size_t)b * T;
    float x2 = xb[t];
    float x1 = (t >= 1) ? xb[t - 1] : 0.f;
    float x0 = (t >= 2) ? xb[t - 2] : 0.f;
#pragma unroll
    for (int o = 0; o < RES; o++) {
        float v = w[o * 3 + 0] * x0 + w[o * 3 + 1] * x1 + w[o * 3 + 2] * x2;
        h[((size_t)(b * RES + o)) * T + t] = v;
    }
}

// ---------------- residual layer, half-split ----------------
// Block = 256 threads = 128 t-positions x 2 halves (half wave-uniform).
// Half h computes conv outputs o = 16h+j and o+32 (j=0..15) -> 16 gates,
// exchanges g via LDS, then computes 16 h_out + 16 skip channels of the 1x1.
// Per-thread: 3072 conv FMA + 1024 1x1 FMA; 2000 blocks (2x R3 parallelism).
template <bool FIRST>
__global__ __launch_bounds__(256) void res_layer(
        const float* __restrict__ h_in, float* __restrict__ h_out,
        float* __restrict__ skip,
        const float* __restrict__ w1p,   // [2][32][3][2][16] this layer
        const float* __restrict__ w2p,   // [2][32][2][16] this layer
        int d) {
    __shared__ float g_lds[32][128];

    int tid = threadIdx.x;
    int t_idx = tid & 127;
    int half = __builtin_amdgcn_readfirstlane(tid >> 7);  // wave-uniform -> SGPR
    int t = blockIdx.x * 128 + t_idx;
    int b = blockIdx.y;

    const float* hb  = h_in + (size_t)b * RES * T;
    const float* w1h = w1p + half * (32 * 3 * 2 * 16);
    const float* w2h = w2p + half * (32 * 2 * 16);

    // clamped tap indices (safe addresses; value zeroed by select)
    int t1 = t - d;     bool v1 = t1 >= 0; int t1c = v1 ? t1 : 0;
    int t0 = t - 2 * d; bool v0 = t0 >= 0; int t0c = v0 ? t0 : 0;

    float acc0[16], acc1[16];
#pragma unroll
    for (int j = 0; j < 16; j++) { acc0[j] = 0.f; acc1[j] = 0.f; }

    for (int c = 0; c < RES; c++) {
        const float* hc = hb + (size_t)c * T;
        float x2 = hc[t];
        float x1 = v1 ? hc[t1c] : 0.f;
        float x0 = v0 ? hc[t0c] : 0.f;
        const float* wc = w1h + c * 96;   // [k][p][16]
#pragma unroll
        for (int j = 0; j < 16; j++) {
            acc0[j] += wc[j] * x0 + wc[32 + j] * x1 + wc[64 + j] * x2;
            acc1[j] += wc[16 + j] * x0 + wc[48 + j] * x1 + wc[80 + j] * x2;
        }
    }

    // gate (local: this thread owns both members of each (o, o+32) pair)
#pragma unroll
    for (int j = 0; j < 16; j++) {
        float g = fast_tanh(acc0[j]) * fast_sigmoid(acc1[j]);
        g_lds[16 * half + j][t_idx] = g;
    }
    __syncthreads();

    // 1x1: this half produces h_out channels [16h,16h+16) and skip channels same
    float zr[16], zs[16];
#pragma unroll
    for (int j = 0; j < 16; j++) { zr[j] = 0.f; zs[j] = 0.f; }
    for (int c = 0; c < RES; c++) {
        float gc = g_lds[c][t_idx];
        const float* vc = w2h + c * 32;   // [p][16]
#pragma unroll
        for (int j = 0; j < 16; j++) {
            zr[j] += vc[j] * gc;
            zs[j] += vc[16 + j] * gc;
        }
    }

    int ob = 16 * half;
#pragma unroll
    for (int j = 0; j < 16; j++) {
        size_t off = ((size_t)(b * RES + ob + j)) * T + t;
        h_out[off] = h_in[off] + zr[j];
    }
#pragma unroll
    for (int j = 0; j < 16; j++) {
        size_t off = ((size_t)(b * SKIPC + ob + j)) * T + t;
        if (FIRST) skip[off] = zs[j];
        else       skip[off] = skip[off] + zs[j];
    }
}

// ---------------- post2: tanh(skip) -> conv 32->16 k3 -> tanh ----------------
__global__ void post2_kernel(const float* __restrict__ skip,
                             const float* __restrict__ w,    // [16][32][3]
                             float* __restrict__ out16) {
    int t = blockIdx.x * blockDim.x + threadIdx.x;
    int b = blockIdx.y;
    float acc[16];
#pragma unroll
    for (int o = 0; o < 16; o++) acc[o] = 0.f;
    for (int c = 0; c < 32; c++) {
        const float* sc = skip + ((size_t)(b * 32 + c)) * T;
        float v2 = fast_tanh(sc[t]);
        float v1 = (t >= 1) ? fast_tanh(sc[t - 1]) : 0.f;
        float v0 = (t >= 2) ? fast_tanh(sc[t - 2]) : 0.f;
#pragma unroll
        for (int o = 0; o < 16; o++) {
            const float* wo = w + (o * 32 + c) * 3;
            acc[o] += wo[0] * v0 + wo[1] * v1 + wo[2] * v2;
        }
    }
#pragma unroll
    for (int o = 0; o < 16; o++)
        out16[((size_t)(b * 16 + o)) * T + t] = fast_tanh(acc[o]);
}

// ---------------- post3: conv 16->8 k3 -> tanh ----------------
__global__ void post3_kernel(const float* __restrict__ in16,
                             const float* __restrict__ w,    // [8][16][3]
                             float* __restrict__ out8) {
    int t = blockIdx.x * blockDim.x + threadIdx.x;
    int b = blockIdx.y;
    float acc[8];
#pragma unroll
    for (int o = 0; o < 8; o++) acc[o] = 0.f;
    for (int c = 0; c < 16; c++) {
        const float* sc = in16 + ((size_t)(b * 16 + c)) * T;
        float v2 = sc[t];
        float v1 = (t >= 1) ? sc[t - 1] : 0.f;
        float v0 = (t >= 2) ? sc[t - 2] : 0.f;
#pragma unroll
        for (int o = 0; o < 8; o++) {
            const float* wo = w + (o * 16 + c) * 3;
            acc[o] += wo[0] * v0 + wo[1] * v1 + wo[2] * v2;
        }
    }
#pragma unroll
    for (int o = 0; o < 8; o++)
        out8[((size_t)(b * 8 + o)) * T + t] = fast_tanh(acc[o]);
}

// ---------------- post4: conv 8->1 k3 -> tanh ----------------
__global__ void post4_kernel(const float* __restrict__ in8,
                             const float* __restrict__ w,    // [1][8][3]
                             float* __restrict__ out1) {
    int t = blockIdx.x * blockDim.x + threadIdx.x;
    int b = blockIdx.y;
    float acc = 0.f;
#pragma unroll
    for (int c = 0; c < 8; c++) {
        const float* sc = in8 + ((size_t)(b * 8 + c)) * T;
        float v2 = sc[t];
        float v1 = (t >= 1) ? sc[t - 1] : 0.f;
        float v0 = (t >= 2) ? sc[t - 2] : 0.f;
        const float* wo = w + c * 3;
        acc += wo[0] * v0 + wo[1] * v1 + wo[2] * v2;
    }
    out1[(size_t)b * T + t] = fast_tanh(acc);
}

// ---------------- vnn head: lin(k=16) + quadratic Volterra ----------------
__global__ void vnn_kernel(const float* __restrict__ in1,   // [B][T]
                           const float* __restrict__ w1,    // [1][1][16]
                           const float* __restrict__ w2,    // [6][1][16]
                           float* __restrict__ out) {       // [B][T]
    int t = blockIdx.x * blockDim.x + threadIdx.x;
    int b = blockIdx.y;
    const float* xb = in1 + (size_t)b * T;
    float tap[16];
#pragma unroll
    for (int k = 0; k < 16; k++) {
        int ti = t - 15 + k;
        tap[k] = (ti >= 0) ? xb[ti] : 0.f;
    }
    float lin = 0.f;
#pragma unroll
    for (int k = 0; k < 16; k++) lin += w1[k] * tap[k];
    float s[6];
#pragma unroll
    for (int q = 0; q < 6; q++) {
        float a = 0.f;
#pragma unroll
        for (int k = 0; k < 16; k++) a += w2[q * 16 + k] * tap[k];
        s[q] = a;
    }
    float quad = s[0] * s[3] + s[1] * s[4] + s[2] * s[5];
    out[(size_t)b * T + t] = lin + quad;
}

extern "C" void kernel_launch(void* const* d_in, const int* in_sizes, int n_in,
                              void* d_out, int out_size, void* d_ws, size_t ws_size,
                              hipStream_t stream) {
    const float* x       = (const float*)d_in[0];
    const float* conv1_w = (const float*)d_in[1];
    const float* res_w1  = (const float*)d_in[2];
    const float* res_w2  = (const float*)d_in[3];
    const float* post2_w = (const float*)d_in[4];
    const float* post3_w = (const float*)d_in[5];
    const float* post4_w = (const float*)d_in[6];
    const float* vnn1_w  = (const float*)d_in[7];
    const float* vnn2_w  = (const float*)d_in[8];
    float* out = (float*)d_out;

    // workspace layout (bytes)
    char* ws = (char*)d_ws;
    const size_t SZ_H    = (size_t)B * RES * T * 4;     // 32.768 MB
    const size_t SZ_O16  = (size_t)B * 16 * T * 4;
    const size_t SZ_O8   = (size_t)B * 8 * T * 4;
    const size_t SZ_O1   = (size_t)B * 1 * T * 4;
    float* hA    = (float*)(ws);
    float* hB    = (float*)(ws + SZ_H);
    float* skip  = (float*)(ws + 2 * SZ_H);
    float* out16 = (float*)(ws + 3 * SZ_H);
    float* out8  = (float*)(ws + 3 * SZ_H + SZ_O16);
    float* out1  = (float*)(ws + 3 * SZ_H + SZ_O16 + SZ_O8);
    float* w1p   = (float*)(ws + 3 * SZ_H + SZ_O16 + SZ_O8 + SZ_O1);
    float* w2p   = (float*)(ws + 3 * SZ_H + SZ_O16 + SZ_O8 + SZ_O1
                               + (size_t)NDIL * 64 * 32 * 3 * 4);

    dim3 blk(256);
    dim3 grd(T / 256, B);     // pre/post kernels: 125 x 8
    dim3 grdR(T / 128, B);    // res layers: 250 x 8 (2000 blocks)

    repack_weights<<<dim3((NDIL * 64 * 32 * 3 + 255) / 256), blk, 0, stream>>>(
        res_w1, res_w2, w1p, w2p);

    conv1_kernel<<<grd, blk, 0, stream>>>(x, conv1_w, hA);

    const float* cur = hA;
    float* nxt = hB;
    for (int l = 0; l < NLAYERS; l++) {
        int i = l % NDIL;
        int d = 1 << i;
        const float* w1l = w1p + (size_t)i * 2 * 32 * 3 * 2 * 16;
        const float* w2l = w2p + (size_t)i * 2 * 32 * 2 * 16;
        if (l == 0)
            res_layer<true><<<grdR, blk, 0, stream>>>(cur, nxt, skip, w1l, w2l, d);
        else
            res_layer<false><<<grdR, blk, 0, stream>>>(cur, nxt, skip, w1l, w2l, d);
        const float* tmp = nxt;
        nxt = (float*)cur;
        cur = tmp;
    }

    post2_kernel<<<grd, blk, 0, stream>>>(skip, post2_w, out16);
    post3_kernel<<<grd, blk, 0, stream>>>(out16, post3_w, out8);
    post4_kernel<<<grd, blk, 0, stream>>>(out8, post4_w, out1);
    vnn_kernel<<<grd, blk, 0, stream>>>(out1, vnn1_w, vnn2_w, out);
}